// Round 6
// baseline (25.431 us; speedup 1.0000x reference)
//
#include <hip/hip_runtime.h>

// Problem constants (from reference):
//   B=8, V=6890, C=16, F=13776, FTOT=B*F=110208, H=W=512, K=1
//   npix = B*H*W*K = 2,097,152  (multiple of 256)
// Output: int32 [B,H,W,K] = channel 0 of barycentric-interpolated
// per-vertex class features, truncated toward zero; 0 for background.
//
// Round 6: round-5 structure (1 px/thread, 32768 waves, fa table prologue,
// no nt) + LDS-staged bary so all streaming loads are perfectly coalesced
// dword loads (stride-12 scalar loads were 36 TA transactions/wave vs 12).

#define VC_C 16

typedef float vfloat4 __attribute__((ext_vector_type(4)));

// Kernel 1: one thread per (face, vertex); 330K threads for latency hiding.
__global__ void gather_face_attr_kernel(const float* __restrict__ vc,
                                        const int* __restrict__ faces,
                                        float* __restrict__ fa_f, int n3) {
    int t = blockIdx.x * blockDim.x + threadIdx.x;
    if (t >= n3) return;
    int f = t / 3;
    int j = t - 3 * f;
    int v = faces[t];
    fa_f[4 * f + j] = vc[(unsigned)v * VC_C];
}

// Kernel 2: 1 pixel per thread; bary staged through LDS with coalesced
// dword loads. Block size 256 == pixels per block; npix % 256 == 0.
__global__ void __launch_bounds__(256, 8)
seg_shader_kernel(const vfloat4* __restrict__ fa,
                  const int* __restrict__ p2f,
                  const float* __restrict__ bary,
                  int* __restrict__ out, int npix) {
    __shared__ float wlds[768];

    int t = threadIdx.x;
    int base = blockIdx.x * 256;
    int i = base + t;
    if (i >= npix) return;  // never taken (npix % 256 == 0), keeps it safe

    // Issue the face index + gather as early as possible.
    int f = p2f[i];

    // Coalesced staging of this block's 768 bary dwords.
    const float* bsrc = bary + (unsigned)base * 3;
    float c0 = bsrc[t];
    float c1 = bsrc[t + 256];
    float c2 = bsrc[t + 512];

    vfloat4 a = fa[f >= 0 ? f : 0];

    wlds[t] = c0;
    wlds[t + 256] = c1;
    wlds[t + 512] = c2;
    __syncthreads();

    float w0 = wlds[3 * t + 0];
    float w1 = wlds[3 * t + 1];
    float w2 = wlds[3 * t + 2];

    float s = w0 * a.x + w1 * a.y + w2 * a.z;
    out[i] = f >= 0 ? (int)s : 0;  // trunc toward zero == astype(int32)
}

// Fallback (no workspace): direct gathers, 1 pixel per thread.
__global__ void seg_shader_direct_kernel(const float* __restrict__ vc,
                                         const int* __restrict__ faces,
                                         const int* __restrict__ p2f,
                                         const float* __restrict__ bary,
                                         int* __restrict__ out, int npix) {
    int i = blockIdx.x * blockDim.x + threadIdx.x;
    if (i >= npix) return;
    int f = p2f[i];
    int r = 0;
    if (f >= 0) {
        int v0 = faces[3 * f + 0];
        int v1 = faces[3 * f + 1];
        int v2 = faces[3 * f + 2];
        float w0 = bary[3 * (long long)i + 0];
        float w1 = bary[3 * (long long)i + 1];
        float w2 = bary[3 * (long long)i + 2];
        float s = w0 * vc[(long long)v0 * VC_C] +
                  w1 * vc[(long long)v1 * VC_C] +
                  w2 * vc[(long long)v2 * VC_C];
        r = (int)s;
    }
    out[i] = r;
}

extern "C" void kernel_launch(void* const* d_in, const int* in_sizes, int n_in,
                              void* d_out, int out_size, void* d_ws, size_t ws_size,
                              hipStream_t stream) {
    const float* verts_class = (const float*)d_in[0];   // [B*V*C] f32
    const int*   faces       = (const int*)d_in[1];     // [FTOT*3] i32
    const int*   pix_to_face = (const int*)d_in[2];     // [npix] i32
    const float* bary        = (const float*)d_in[3];   // [npix*3] f32
    int*         out         = (int*)d_out;             // [npix] i32

    const int ftot = in_sizes[1] / 3;
    const int npix = out_size;
    const size_t fa_bytes = (size_t)ftot * 4 * sizeof(float);

    if (d_ws != nullptr && ws_size >= fa_bytes && (npix % 256) == 0) {
        float* fa_f = (float*)d_ws;
        {
            int n3 = ftot * 3;
            int threads = 256;
            int blocks = (n3 + threads - 1) / threads;
            gather_face_attr_kernel<<<blocks, threads, 0, stream>>>(
                verts_class, faces, fa_f, n3);
        }
        {
            int threads = 256;
            int blocks = npix / 256;
            seg_shader_kernel<<<blocks, threads, 0, stream>>>(
                (const vfloat4*)d_ws, pix_to_face, bary, out, npix);
        }
    } else {
        int threads = 256;
        int blocks = (npix + threads - 1) / threads;
        seg_shader_direct_kernel<<<blocks, threads, 0, stream>>>(
            verts_class, faces, pix_to_face, bary, out, npix);
    }
}